// Round 6
// baseline (286.756 us; speedup 1.0000x reference)
//
#include <hip/hip_runtime.h>

typedef short bf16x8 __attribute__((ext_vector_type(8)));
typedef float f32x4 __attribute__((ext_vector_type(4)));
typedef unsigned short us8 __attribute__((ext_vector_type(8)));

__device__ __forceinline__ unsigned short f2bf(float f) {
    unsigned int u = __float_as_uint(f);
    u += 0x7fffu + ((u >> 16) & 1u);   // round-to-nearest-even
    return (unsigned short)(u >> 16);
}

__device__ __forceinline__ void gload16(const void* g, void* l) {
    __builtin_amdgcn_global_load_lds((const __attribute__((address_space(1))) void*)g,
                                     (__attribute__((address_space(3))) void*)l, 16, 0, 0);
}

__device__ __forceinline__ bf16x8 cvt_pk8(float4 a, float4 b) {
    union { bf16x8 h; unsigned int u[4]; } r;
    asm("v_cvt_pk_bf16_f32 %0, %1, %2" : "=v"(r.u[0]) : "v"(a.x), "v"(a.y));
    asm("v_cvt_pk_bf16_f32 %0, %1, %2" : "=v"(r.u[1]) : "v"(a.z), "v"(a.w));
    asm("v_cvt_pk_bf16_f32 %0, %1, %2" : "=v"(r.u[2]) : "v"(b.x), "v"(b.y));
    asm("v_cvt_pk_bf16_f32 %0, %1, %2" : "=v"(r.u[3]) : "v"(b.z), "v"(b.w));
    return r.h;
}

// ---- transpose + cast fp32 -> bf16 bits: out[Cc][R] = cast(in[R][Cc]) ----
__global__ __launch_bounds__(256) void transpose_cast_kernel(
    const float* __restrict__ in, unsigned short* __restrict__ out, int R, int Cc) {
    __shared__ alignas(16) unsigned short sT[64][65];
    const int r0 = blockIdx.x * 64, c0 = blockIdx.y * 64;
    const int t = threadIdx.x;
#pragma unroll
    for (int p = 0; p < 16; ++p) {
        int flat = p * 256 + t;
        int r = flat >> 6, c = flat & 63;
        sT[c][r] = f2bf(in[(size_t)(r0 + r) * Cc + (c0 + c)]);
    }
    __syncthreads();
#pragma unroll
    for (int p = 0; p < 16; ++p) {
        int flat = p * 256 + t;
        int c = flat >> 6, r = flat & 63;
        out[(size_t)(c0 + c) * R + (r0 + r)] = sT[c][r];
    }
}

// ---- small MFMA GEMM (BM=64, 4 waves): C[M][N] = A[M][K] @ (BT[N][K])^T ----
// AMODE 0: A already bf16. AMODE 1: A fp32 -> bf16 during staging.
// TOUT: write bf16 transposed C[N][M].
template<int BN, int WM, int WN, int AMODE, bool TOUT, typename OutT>
__global__ __launch_bounds__(256) void gemm_kernel(
    const void* __restrict__ Aptr, const unsigned short* __restrict__ BT,
    OutT* __restrict__ C, int M, int N, int K) {
    constexpr int BM = 64, BK = 64, LDW = 72;
    constexpr int MF = BM / WM / 16;
    constexpr int NF = BN / WN / 16;
    __shared__ alignas(16) unsigned short sA[BM * LDW];
    __shared__ alignas(16) unsigned short sB[BN * LDW];
    const int t = threadIdx.x;
    const int w = t >> 6, l = t & 63;
    const int wr = w / WN, wc = w % WN;
    const int m0 = blockIdx.x * BM;

    f32x4 acc[MF][NF] = {};

    for (int k0 = 0; k0 < K; k0 += BK) {
        if constexpr (AMODE == 1) {
            const float* A32 = (const float*)Aptr;
#pragma unroll
            for (int p = 0; p < 4; ++p) {
                int flat = p * 256 + t;
                int row = flat >> 4, c4 = flat & 15;
                float4 v = *(const float4*)&A32[(size_t)(m0 + row) * K + k0 + c4 * 4];
                *(ushort4*)&sA[row * LDW + c4 * 4] =
                    make_ushort4(f2bf(v.x), f2bf(v.y), f2bf(v.z), f2bf(v.w));
            }
        } else {
            const unsigned short* A16 = (const unsigned short*)Aptr;
#pragma unroll
            for (int p = 0; p < 2; ++p) {
                int flat = p * 256 + t;
                int row = flat >> 3, c8 = flat & 7;
                us8 v = *(const us8*)&A16[(size_t)(m0 + row) * K + k0 + c8 * 8];
                *(us8*)&sA[row * LDW + c8 * 8] = v;
            }
        }
#pragma unroll
        for (int p = 0; p < BN * 8 / 256; ++p) {
            int flat = p * 256 + t;
            int row = flat >> 3, c8 = flat & 7;
            us8 v = *(const us8*)&BT[(size_t)row * K + k0 + c8 * 8];
            *(us8*)&sB[row * LDW + c8 * 8] = v;
        }
        __syncthreads();
#pragma unroll
        for (int kk = 0; kk < BK; kk += 32) {
            bf16x8 av[MF], bv[NF];
#pragma unroll
            for (int m = 0; m < MF; ++m)
                av[m] = *(const bf16x8*)&sA[(wr * (BM / WM) + m * 16 + (l & 15)) * LDW + kk + (l >> 4) * 8];
#pragma unroll
            for (int n = 0; n < NF; ++n)
                bv[n] = *(const bf16x8*)&sB[(wc * (BN / WN) + n * 16 + (l & 15)) * LDW + kk + (l >> 4) * 8];
#pragma unroll
            for (int m = 0; m < MF; ++m)
#pragma unroll
                for (int n = 0; n < NF; ++n)
                    acc[m][n] = __builtin_amdgcn_mfma_f32_16x16x32_bf16(av[m], bv[n], acc[m][n], 0, 0, 0);
        }
        __syncthreads();
    }

#pragma unroll
    for (int m = 0; m < MF; ++m) {
#pragma unroll
        for (int n = 0; n < NF; ++n) {
            const int col = wc * (BN / WN) + n * 16 + (l & 15);
            const int rb = m0 + wr * (BM / WM) + m * 16 + ((l >> 4) << 2);
            float v0 = acc[m][n][0], v1 = acc[m][n][1], v2 = acc[m][n][2], v3 = acc[m][n][3];
            if constexpr (TOUT) {
                ushort4 o = make_ushort4(f2bf(v0), f2bf(v1), f2bf(v2), f2bf(v3));
                *(ushort4*)((unsigned short*)C + (size_t)col * M + rb) = o;
            } else {
                C[(size_t)(rb + 0) * N + col] = (OutT)v0;
                C[(size_t)(rb + 1) * N + col] = (OutT)v1;
                C[(size_t)(rb + 2) * N + col] = (OutT)v2;
                C[(size_t)(rb + 3) * N + col] = (OutT)v3;
            }
        }
    }
}

// ---- big adj-streaming GEMM: BM=32, no K-split, glds 2-phase double-buffer ----
// C = adj[M][K] @ (BT[N][K])^T.  OUTMODE 0: fp32 row-major. 1: bf16 relu row-major.
// LDS linear; content swizzled via pre-swizzled GLOBAL source (rule #21):
//   A (fp32, 16x16B units/row): phys unit p holds logical p^(r&15)
//   B (bf16,  8x16B slots/row): phys slot  s holds logical s^(r&7)
// (read/write swizzle math validated in R5's passing run — unchanged)
template<int BM, int BN, int WM, int WN, int OUTMODE>
__global__ __launch_bounds__(256) void big_gemm_kernel(
    const float* __restrict__ A, const unsigned short* __restrict__ BT,
    void* __restrict__ Cout, int M, int N, int K) {
    constexpr int BK = 64, NW = 4;
    constexpr int MF = BM / WM / 16, NF = BN / WN / 16;
    constexpr int AREG = BM * BK * 4 / 1024;   // 1KB wave-regions of A
    constexpr int BREG = BN * BK * 2 / 1024;   // 1KB wave-regions of B
    __shared__ alignas(16) float sA[2][BM * BK];
    __shared__ alignas(16) unsigned short sB[2][BN * BK];
    const int t = threadIdx.x, w = t >> 6, l = t & 63;
    const int wr = w / WN, wc = w % WN;
    const int m0 = blockIdx.x * BM;
    const int NT = K / BK;

    auto STAGE = [&](int buf, int k0) {
#pragma unroll
        for (int j = 0; j < AREG / NW; ++j) {
            int q = w + j * NW;
            int r = q * 4 + (l >> 4);
            int col = ((l & 15) ^ (r & 15)) * 4;
            gload16(&A[(size_t)(m0 + r) * K + k0 + col], (char*)sA[buf] + q * 1024);
        }
#pragma unroll
        for (int j = 0; j < BREG / NW; ++j) {
            int q = w + j * NW;
            int r = q * 8 + (l >> 3);
            int col = ((l & 7) ^ (r & 7)) * 8;
            gload16(&BT[(size_t)r * K + k0 + col], (char*)sB[buf] + q * 1024);
        }
    };

    f32x4 acc[MF][NF] = {};

    STAGE(0, 0);
    __syncthreads();                       // tile 0 ready
    int cur = 0;
    for (int tt = 0; tt < NT; ++tt) {
        if (tt + 1 < NT) STAGE(cur ^ 1, (tt + 1) * BK);   // in flight during compute
#pragma unroll
        for (int kk = 0; kk < BK; kk += 32) {
            bf16x8 av[MF], bv[NF];
#pragma unroll
            for (int m = 0; m < MF; ++m) {
                int r = wr * (BM / WM) + m * 16 + (l & 15);
                int p0 = ((kk >> 2) + (l >> 4) * 2) ^ (r & 15);
                float4 fa = *(const float4*)&sA[cur][r * 64 + p0 * 4];
                float4 fb = *(const float4*)&sA[cur][r * 64 + (p0 ^ 1) * 4];
                av[m] = cvt_pk8(fa, fb);
            }
#pragma unroll
            for (int n = 0; n < NF; ++n) {
                int r = wc * (BN / WN) + n * 16 + (l & 15);
                int s = ((kk >> 3) + (l >> 4)) ^ (r & 7);
                bv[n] = *(const bf16x8*)&sB[cur][r * 64 + s * 8];
            }
#pragma unroll
            for (int m = 0; m < MF; ++m)
#pragma unroll
                for (int n = 0; n < NF; ++n)
                    acc[m][n] = __builtin_amdgcn_mfma_f32_16x16x32_bf16(av[m], bv[n], acc[m][n], 0, 0, 0);
        }
        __syncthreads();   // drains next tile's DMA + guards buffer reuse
        cur ^= 1;
    }

#pragma unroll
    for (int m = 0; m < MF; ++m)
#pragma unroll
        for (int n = 0; n < NF; ++n) {
            const int col = wc * (BN / WN) + n * 16 + (l & 15);
            const int rb = m0 + wr * (BM / WM) + m * 16 + ((l >> 4) << 2);
#pragma unroll
            for (int j = 0; j < 4; ++j) {
                if constexpr (OUTMODE == 0)
                    ((float*)Cout)[(size_t)(rb + j) * N + col] = acc[m][n][j];
                else
                    ((unsigned short*)Cout)[(size_t)(rb + j) * N + col] =
                        f2bf(fmaxf(acc[m][n][j], 0.f));
            }
        }
}

// ---- head: log_softmax over rows of o[8192][64]; one wave per row ----
__global__ __launch_bounds__(256) void head2_kernel(
    const float* __restrict__ p, float* __restrict__ out, int M) {
    const int t = threadIdx.x, w = t >> 6, l = t & 63;
#pragma unroll
    for (int rr = 0; rr < 4; ++rr) {
        int i = blockIdx.x * 16 + w * 4 + rr;
        size_t off = (size_t)i * 64 + l;
        float v = p[off];
        float mx = v;
#pragma unroll
        for (int o = 32; o; o >>= 1) mx = fmaxf(mx, __shfl_xor(mx, o));
        float d0 = v - mx;
        float e = __expf(d0);
#pragma unroll
        for (int o = 32; o; o >>= 1) e += __shfl_xor(e, o);
        out[off] = d0 - __logf(e);
    }
}

extern "C" void kernel_launch(void* const* d_in, const int* in_sizes, int n_in,
                              void* d_out, int out_size, void* d_ws, size_t ws_size,
                              hipStream_t stream) {
    const float* adj = (const float*)d_in[0];
    const float* x   = (const float*)d_in[1];
    const float* W1  = (const float*)d_in[2];
    const float* W2  = (const float*)d_in[3];
    float* out = (float*)d_out;

    const int M = 8192, K = 8192;
    char* ws = (char*)d_ws;
    // ws layout (~11.2 MB; ws_size ~1 GB):
    unsigned short* t1B = (unsigned short*)ws;                 // 4 MB: relu(adj@z) bf16 [8192][256]
    float*          ob  = (float*)(ws + 4194304);              // 2 MB: o fp32 [8192][64]
    unsigned short* zT  = (unsigned short*)(ws + 6291456);     // 4 MB: z^T  bf16 [256][8192]
    unsigned short* hwT = (unsigned short*)(ws + 10485760);    // 1 MB: hw^T bf16 [64][8192]
    unsigned short* W1T = (unsigned short*)(ws + 11534336);    // 128 KB
    unsigned short* W2T = (unsigned short*)(ws + 11665408);    // 32 KB

    transpose_cast_kernel<<<dim3(4, 4), 256, 0, stream>>>(W1, W1T, 256, 256);
    transpose_cast_kernel<<<dim3(4, 1), 256, 0, stream>>>(W2, W2T, 256, 64);
    // z^T = (x @ W1)^T, bf16
    gemm_kernel<256, 1, 4, 1, true, unsigned short>
        <<<dim3(M / 64), 256, 0, stream>>>(x, W1T, zT, M, 256, 256);
    // t1 = relu(adj @ z), bf16, direct (256 blocks, no K-split; LDS 80 KB)
    big_gemm_kernel<32, 256, 1, 4, 1>
        <<<dim3(M / 32), 256, 0, stream>>>(adj, zT, t1B, M, 256, K);
    // hw^T = (t1 @ W2)^T, bf16
    gemm_kernel<64, 2, 2, 0, true, unsigned short>
        <<<dim3(M / 64), 256, 0, stream>>>(t1B, W2T, hwT, M, 64, 256);
    // o = adj @ hw, fp32, direct (256 blocks; LDS 32 KB)
    big_gemm_kernel<32, 64, 2, 2, 0>
        <<<dim3(M / 32), 256, 0, stream>>>(adj, hwT, ob, M, 64, K);
    head2_kernel<<<dim3(M / 16), 256, 0, stream>>>(ob, out, M);
}

// Round 7
// 188.163 us; speedup vs baseline: 1.5240x; 1.5240x over previous
//
#include <hip/hip_runtime.h>

typedef short bf16x8 __attribute__((ext_vector_type(8)));
typedef float f32x4 __attribute__((ext_vector_type(4)));
typedef unsigned short us8 __attribute__((ext_vector_type(8)));

__device__ __forceinline__ unsigned short f2bf(float f) {
    unsigned int u = __float_as_uint(f);
    u += 0x7fffu + ((u >> 16) & 1u);   // round-to-nearest-even
    return (unsigned short)(u >> 16);
}

__device__ __forceinline__ void gload16(const void* g, void* l) {
    __builtin_amdgcn_global_load_lds((const __attribute__((address_space(1))) void*)g,
                                     (__attribute__((address_space(3))) void*)l, 16, 0, 0);
}

__device__ __forceinline__ bf16x8 cvt_pk8(float4 a, float4 b) {
    union { bf16x8 h; unsigned int u[4]; } r;
    asm("v_cvt_pk_bf16_f32 %0, %1, %2" : "=v"(r.u[0]) : "v"(a.x), "v"(a.y));
    asm("v_cvt_pk_bf16_f32 %0, %1, %2" : "=v"(r.u[1]) : "v"(a.z), "v"(a.w));
    asm("v_cvt_pk_bf16_f32 %0, %1, %2" : "=v"(r.u[2]) : "v"(b.x), "v"(b.y));
    asm("v_cvt_pk_bf16_f32 %0, %1, %2" : "=v"(r.u[3]) : "v"(b.z), "v"(b.w));
    return r.h;
}

template<int N> __device__ __forceinline__ void waitvm() {
    static_assert(N == 0 || N == 4 || N == 5, "unsupported vmcnt");
    if constexpr (N == 0) asm volatile("s_waitcnt vmcnt(0)" ::: "memory");
    else if constexpr (N == 4) asm volatile("s_waitcnt vmcnt(4)" ::: "memory");
    else if constexpr (N == 5) asm volatile("s_waitcnt vmcnt(5)" ::: "memory");
}

// ---- transpose + cast fp32 -> bf16 bits: out[Cc][R] = cast(in[R][Cc]) ----
__global__ __launch_bounds__(256) void transpose_cast_kernel(
    const float* __restrict__ in, unsigned short* __restrict__ out, int R, int Cc) {
    __shared__ alignas(16) unsigned short sT[64][65];
    const int r0 = blockIdx.x * 64, c0 = blockIdx.y * 64;
    const int t = threadIdx.x;
#pragma unroll
    for (int p = 0; p < 16; ++p) {
        int flat = p * 256 + t;
        int r = flat >> 6, c = flat & 63;
        sT[c][r] = f2bf(in[(size_t)(r0 + r) * Cc + (c0 + c)]);
    }
    __syncthreads();
#pragma unroll
    for (int p = 0; p < 16; ++p) {
        int flat = p * 256 + t;
        int c = flat >> 6, r = flat & 63;
        out[(size_t)(c0 + c) * R + (r0 + r)] = sT[c][r];
    }
}

// ---- small MFMA GEMM (BM=64, 4 waves): C[M][N] = A[M][K] @ (BT[N][K])^T ----
// AMODE 1: A fp32 -> bf16 during staging.
// AMODE 2: A = relu(sum of 4 fp32 slabs, stride aslab) -> bf16 during staging.
// TOUT: write bf16 transposed C[N][M].
template<int BN, int WM, int WN, int AMODE, bool TOUT, typename OutT>
__global__ __launch_bounds__(256) void gemm_kernel(
    const void* __restrict__ Aptr, const unsigned short* __restrict__ BT,
    OutT* __restrict__ C, int M, int N, int K, long aslab) {
    constexpr int BM = 64, BK = 64, LDW = 72;
    constexpr int MF = BM / WM / 16;
    constexpr int NF = BN / WN / 16;
    __shared__ alignas(16) unsigned short sA[BM * LDW];
    __shared__ alignas(16) unsigned short sB[BN * LDW];
    const int t = threadIdx.x;
    const int w = t >> 6, l = t & 63;
    const int wr = w / WN, wc = w % WN;
    const int m0 = blockIdx.x * BM;

    f32x4 acc[MF][NF] = {};

    for (int k0 = 0; k0 < K; k0 += BK) {
        const float* A32 = (const float*)Aptr;
#pragma unroll
        for (int p = 0; p < 4; ++p) {
            int flat = p * 256 + t;
            int row = flat >> 4, c4 = flat & 15;
            size_t base = (size_t)(m0 + row) * K + k0 + c4 * 4;
            float4 v = *(const float4*)&A32[base];
            if constexpr (AMODE == 2) {
                float4 b = *(const float4*)&A32[aslab + base];
                float4 c = *(const float4*)&A32[2 * aslab + base];
                float4 d = *(const float4*)&A32[3 * aslab + base];
                v.x = fmaxf(v.x + b.x + c.x + d.x, 0.f);
                v.y = fmaxf(v.y + b.y + c.y + d.y, 0.f);
                v.z = fmaxf(v.z + b.z + c.z + d.z, 0.f);
                v.w = fmaxf(v.w + b.w + c.w + d.w, 0.f);
            }
            ushort4 o = make_ushort4(f2bf(v.x), f2bf(v.y), f2bf(v.z), f2bf(v.w));
            *(ushort4*)&sA[row * LDW + c4 * 4] = o;
        }
#pragma unroll
        for (int p = 0; p < BN * 8 / 256; ++p) {
            int flat = p * 256 + t;
            int row = flat >> 3, c8 = flat & 7;
            us8 v = *(const us8*)&BT[(size_t)row * K + k0 + c8 * 8];
            *(us8*)&sB[row * LDW + c8 * 8] = v;
        }
        __syncthreads();
#pragma unroll
        for (int kk = 0; kk < BK; kk += 32) {
            bf16x8 av[MF], bv[NF];
#pragma unroll
            for (int m = 0; m < MF; ++m)
                av[m] = *(const bf16x8*)&sA[(wr * (BM / WM) + m * 16 + (l & 15)) * LDW + kk + (l >> 4) * 8];
#pragma unroll
            for (int n = 0; n < NF; ++n)
                bv[n] = *(const bf16x8*)&sB[(wc * (BN / WN) + n * 16 + (l & 15)) * LDW + kk + (l >> 4) * 8];
#pragma unroll
            for (int m = 0; m < MF; ++m)
#pragma unroll
                for (int n = 0; n < NF; ++n)
                    acc[m][n] = __builtin_amdgcn_mfma_f32_16x16x32_bf16(av[m], bv[n], acc[m][n], 0, 0, 0);
        }
        __syncthreads();
    }

#pragma unroll
    for (int m = 0; m < MF; ++m) {
#pragma unroll
        for (int n = 0; n < NF; ++n) {
            const int col = wc * (BN / WN) + n * 16 + (l & 15);
            const int rb = m0 + wr * (BM / WM) + m * 16 + ((l >> 4) << 2);
            float v0 = acc[m][n][0], v1 = acc[m][n][1], v2 = acc[m][n][2], v3 = acc[m][n][3];
            if constexpr (TOUT) {
                ushort4 o = make_ushort4(f2bf(v0), f2bf(v1), f2bf(v2), f2bf(v3));
                *(ushort4*)((unsigned short*)C + (size_t)col * M + rb) = o;
            } else {
                C[(size_t)(rb + 0) * N + col] = (OutT)v0;
                C[(size_t)(rb + 1) * N + col] = (OutT)v1;
                C[(size_t)(rb + 2) * N + col] = (OutT)v2;
                C[(size_t)(rb + 3) * N + col] = (OutT)v3;
            }
        }
    }
}

// ---- big adj-streaming GEMM: BK=32, 3-buffer ring, counted vmcnt ----
// C (fp32 K-split partial slab z) = adj[M][K] @ (BT[N][K])^T
// LDS physical layouts (glds dest is linear: base + lane*16):
//   A: row-major [BM][32] f32, 128 B/row = 8 16B units; phys unit p of row r
//      holds logical unit p^(r&7)  (global source pre-swizzled).
//   B: row-major [BN][32] bf16, 64 B/row = 4 16B slots; phys slot p of row r
//      holds logical slot (p-(r>>2))&3.
// Bank check (frag reads, 16 consecutive rows/lane-group): A banks 4*(u^(r&7))
// -> 8 banks x 2-way (free, m136); B banks (16r+4s)%32 -> 2-way (free).
template<int BM, int BN, int WM, int WN, int THREADS, int IPT>
__global__ __launch_bounds__(THREADS, 2) void ring_gemm_kernel(
    const float* __restrict__ A, const unsigned short* __restrict__ BT,
    float* __restrict__ C, int M, int N, int K) {
    constexpr int BK = 32;
    constexpr int NW = THREADS / 64;
    constexpr int MF = BM / WM / 16, NF = BN / WN / 16;
    constexpr int AISS = BM * BK * 4 / 1024;    // 1KB A issues per tile
    constexpr int BISS = BN * BK * 2 / 1024;    // 1KB B issues per tile
    constexpr int AIPW = AISS / NW, BIPW = BISS / NW;
    static_assert(AIPW * NW == AISS && BIPW * NW == BISS, "issue split");
    static_assert(IPT == AIPW + BIPW, "IPT mismatch");
    __shared__ alignas(16) float sA[3][BM * BK];
    __shared__ alignas(16) unsigned short sB[3][BN * BK];
    const int t = threadIdx.x, w = t >> 6, l = t & 63;
    const int wr = w / WN, wc = w % WN;
    const int m0 = blockIdx.x * BM;
    const int klen = K / gridDim.z, kbeg = blockIdx.z * klen;
    const int NT = klen / BK;
    float* Cp = C + (size_t)blockIdx.z * M * N;

    auto STAGE = [&](int buf, int k0) {
#pragma unroll
        for (int j = 0; j < AIPW; ++j) {
            int q = w * AIPW + j;
            int r = q * 8 + (l >> 3);               // 8 rows per 1KB issue
            int u = (l & 7) ^ (r & 7);              // logical unit for phys l&7
            gload16(&A[(size_t)(m0 + r) * K + k0 + u * 4], (char*)&sA[buf][0] + q * 1024);
        }
#pragma unroll
        for (int j = 0; j < BIPW; ++j) {
            int q = w * BIPW + j;
            int r = q * 16 + (l >> 2);              // 16 rows per 1KB issue
            int s = ((l & 3) - (r >> 2)) & 3;       // logical slot for phys l&3
            gload16(&BT[(size_t)r * K + k0 + s * 8], (char*)&sB[buf][0] + q * 1024);
        }
    };

    f32x4 acc[MF][NF] = {};

    STAGE(0, kbeg);
    STAGE(1, kbeg + BK);
    waitvm<IPT>();                       // tile 0 landed (tile 1 in flight)
    __builtin_amdgcn_sched_barrier(0);
    __builtin_amdgcn_s_barrier();
    __builtin_amdgcn_sched_barrier(0);

    int cur = 0;
    for (int tt = 0; tt < NT; ++tt) {
        if (tt + 2 < NT) {
            int sb = (cur >= 1) ? cur - 1 : cur + 2;   // (cur+2)%3
            STAGE(sb, kbeg + (tt + 2) * BK);
        }
        {
            bf16x8 av[MF], bv[NF];
#pragma unroll
            for (int m = 0; m < MF; ++m) {
                int r = wr * (BM / WM) + m * 16 + (l & 15);
                int u0 = ((l >> 4) * 2) ^ (r & 7);     // phys unit of logical low half
                const float* base = &sA[cur][r * 32];
                float4 fa = *(const float4*)&base[u0 * 4];
                float4 fb = *(const float4*)&base[(u0 ^ 1) * 4];
                av[m] = cvt_pk8(fa, fb);               // fa=logical k-low, fb=k-high
            }
#pragma unroll
            for (int n = 0; n < NF; ++n) {
                int r = wc * (BN / WN) + n * 16 + (l & 15);
                int s = ((l >> 4) + (r >> 2)) & 3;     // phys slot of logical l>>4
                bv[n] = *(const bf16x8*)&sB[cur][r * 32 + s * 8];
            }
#pragma unroll
            for (int m = 0; m < MF; ++m)
#pragma unroll
                for (int n = 0; n < NF; ++n)
                    acc[m][n] = __builtin_amdgcn_mfma_f32_16x16x32_bf16(av[m], bv[n], acc[m][n], 0, 0, 0);
        }
        // wait tile tt+1 complete (tile tt+2 stays in flight), then collective
        if (tt + 2 < NT) waitvm<IPT>(); else waitvm<0>();
        __builtin_amdgcn_sched_barrier(0);
        __builtin_amdgcn_s_barrier();
        __builtin_amdgcn_sched_barrier(0);
        cur = (cur == 2) ? 0 : cur + 1;
    }

#pragma unroll
    for (int m = 0; m < MF; ++m)
#pragma unroll
        for (int n = 0; n < NF; ++n) {
            const int col = wc * (BN / WN) + n * 16 + (l & 15);
            const int rb = m0 + wr * (BM / WM) + m * 16 + ((l >> 4) << 2);
#pragma unroll
            for (int j = 0; j < 4; ++j)
                Cp[(size_t)(rb + j) * N + col] = acc[m][n][j];
        }
}

// ---- head: reduce 8 fp32 partial slabs of o[8192][64], then log_softmax rows ----
__global__ __launch_bounds__(256) void head2_kernel(
    const float* __restrict__ p, float* __restrict__ out, int M) {
    const int t = threadIdx.x, w = t >> 6, l = t & 63;
    const size_t stride = (size_t)M * 64;
#pragma unroll
    for (int rr = 0; rr < 4; ++rr) {
        int i = blockIdx.x * 16 + w * 4 + rr;
        size_t off = (size_t)i * 64 + l;
        float v = 0.f;
#pragma unroll
        for (int s = 0; s < 8; ++s) v += p[s * stride + off];
        float mx = v;
#pragma unroll
        for (int o = 32; o; o >>= 1) mx = fmaxf(mx, __shfl_xor(mx, o));
        float d0 = v - mx;
        float e = __expf(d0);
#pragma unroll
        for (int o = 32; o; o >>= 1) e += __shfl_xor(e, o);
        out[off] = d0 - __logf(e);
    }
}

extern "C" void kernel_launch(void* const* d_in, const int* in_sizes, int n_in,
                              void* d_out, int out_size, void* d_ws, size_t ws_size,
                              hipStream_t stream) {
    const float* adj = (const float*)d_in[0];
    const float* x   = (const float*)d_in[1];
    const float* W1  = (const float*)d_in[2];
    const float* W2  = (const float*)d_in[3];
    float* out = (float*)d_out;

    const int M = 8192, K = 8192;
    char* ws = (char*)d_ws;
    // ws layout (~55.8 MB; ws_size ~1 GB):
    float*          pbuf1 = (float*)ws;                        // 32 MB: 4 slabs t1 partials [8192][256]
    float*          pbuf2 = (float*)(ws + 33554432);           // 16 MB: 8 slabs o partials  [8192][64]
    unsigned short* zT    = (unsigned short*)(ws + 50331648);  //  4 MB: z^T  bf16 [256][8192]
    unsigned short* hwT   = (unsigned short*)(ws + 54525952);  //  1 MB: hw^T bf16 [64][8192]
    unsigned short* W1T   = (unsigned short*)(ws + 55574528);  // 128 KB
    unsigned short* W2T   = (unsigned short*)(ws + 55705600);  // 32 KB

    transpose_cast_kernel<<<dim3(4, 4), 256, 0, stream>>>(W1, W1T, 256, 256);
    transpose_cast_kernel<<<dim3(4, 1), 256, 0, stream>>>(W2, W2T, 256, 64);
    // z^T = (x @ W1)^T, bf16
    gemm_kernel<256, 1, 4, 1, true, unsigned short>
        <<<dim3(M / 64), 256, 0, stream>>>(x, W1T, zT, M, 256, 256, 0);
    // t1 partials = adj @ z  (K-split 4; 256 blocks, 8 waves, 96 KB LDS, IPT=4)
    ring_gemm_kernel<128, 256, 2, 4, 512, 4>
        <<<dim3(M / 128, 1, 4), 512, 0, stream>>>(adj, zT, pbuf1, M, 256, K);
    // hw^T = (relu(sum of 4 t1 slabs) @ W2)^T, bf16
    gemm_kernel<64, 2, 2, 2, true, unsigned short>
        <<<dim3(M / 64), 256, 0, stream>>>(pbuf1, W2T, hwT, M, 64, 256, (long)M * 256);
    // o partials = adj @ hw  (K-split 8; 512 blocks, 4 waves, 60 KB LDS -> 2/CU, IPT=5)
    ring_gemm_kernel<128, 64, 2, 2, 256, 5>
        <<<dim3(M / 128, 1, 8), 256, 0, stream>>>(adj, hwT, pbuf2, M, 64, K);
    head2_kernel<<<dim3(M / 16), 256, 0, stream>>>(pbuf2, out, M);
}